// Round 13
// baseline (225.058 us; speedup 1.0000x reference)
//
#include <hip/hip_runtime.h>

// ---------------------------------------------------------------------------
// GNN predictor (fp32 I/O). Round 22 = R21 (224.8us) plus:
//   - k_preSort: k_pre and k_sortA MERGED into one 512-thread launch
//     (block-split; they're independent, both only need prep) -> overlap
//     instead of serialization. Sort blocks first (feed bucketB2). LDS is
//     a 36KB union (sort: 8KB hist + 16KB sorted; pre: 8 waves x 1152f
//     tiles). Pre path drops its barrier: tiles are wave-private and
//     same-wave LDS write->read needs no __syncthreads.
//   - fused: unpack/+padd/lrelu chain rewritten as float2 ext-vector ops
//     -> v_pk_add/mul/max_f32 (saves ~12 VALU/batch of ~90).
// R21 LESSON: atomic-free block-local sort + run-gather beat the global-
// reservation scheme by 10.6us. R20: same-address device RMW storms
// serialize at the fabric. R19: MFMA + preloaded frags + hi/lo bf16 3-term
// is the fix for per-node MLPs (58->19us). R9: threadIdx-derived weight
// addrs -> per-lane vector loads. R8: __shfl/bpermute are LDS-pipe ops.
// R7: keep fused/node split (VGPR). R4: per-edge device atomics = 64B RMW.
// R10: no global work cursor. Fused VALU diet verified R11.
// ---------------------------------------------------------------------------

#define LRELU_SLOPE 0.01f
#define BUCK_SHIFT 8                  // 256 nodes per bucket
#define TANH_SCALE 2.8853900817779268f  // 2*log2(e)
#define EPB 4096                      // edges per sort block

constexpr int OFF_B1E   = 2432;       // [32]
constexpr int OFF_B2E   = 4512;       // [64]      pre-scaled by TANH_SCALE
constexpr int OFF_B2N   = 11104;      // [64]
constexpr int OFF_B1N   = 11168;      // [32]
constexpr int OFF_W1POS = 11200;      // [32] float2 (W1e rows 2,3)
constexpr int W_TOTAL   = 11264;

typedef __bf16 bf16x8 __attribute__((ext_vector_type(8)));
typedef float  f32x4  __attribute__((ext_vector_type(4)));
typedef float  f32x2  __attribute__((ext_vector_type(2)));

__device__ __forceinline__ unsigned f2bf_pair(float f0, float f1) {
    unsigned u0 = __float_as_uint(f0), u1 = __float_as_uint(f1);
    unsigned r0 = (u0 + 0x7fffu + ((u0 >> 16) & 1u)) >> 16;   // RNE
    unsigned r1 = (u1 + 0x7fffu + ((u1 >> 16) & 1u)) >> 16;
    return r0 | (r1 << 16);
}
__device__ __forceinline__ float bf_round(float f) {  // f32 value of RNE bf16(f)
    unsigned u = __float_as_uint(f);
    return __uint_as_float((u + 0x7fffu + ((u >> 16) & 1u)) & 0xffff0000u);
}
__device__ __forceinline__ bf16x8 pack8(float a0, float a1, float a2, float a3,
                                        float a4, float a5, float a6, float a7) {
    union { uint4 u; bf16x8 b; } c;
    c.u.x = f2bf_pair(a0, a1); c.u.y = f2bf_pair(a2, a3);
    c.u.z = f2bf_pair(a4, a5); c.u.w = f2bf_pair(a6, a7);
    return c.b;
}
__device__ __forceinline__ f32x2 unpk2(unsigned p) {
    f32x2 r;
    r.x = __uint_as_float(p << 16);
    r.y = __uint_as_float(p & 0xffff0000u);
    return r;
}

// X96 row maps: X = [h(64) | pos.x,pos.y,0,0,u(8),0*20]
__device__ __forceinline__ float w1e_x96(const float* W1e, int i, int j) {
    if (i < 64) return W1e[(12 + i) * 32 + j];
    if (i == 64) return W1e[0 * 32 + j];
    if (i == 65) return W1e[1 * 32 + j];
    if (i >= 68 && i < 76) return W1e[(4 + i - 68) * 32 + j];
    return 0.f;
}
__device__ __forceinline__ float w1n_x96(const float* W1n, int i, int j) {
    if (i < 64) return W1n[(2 + i) * 32 + j];
    if (i == 64) return W1n[0 * 32 + j];
    if (i == 65) return W1n[1 * 32 + j];
    if (i >= 68 && i < 76) return W1n[(130 + i - 68) * 32 + j];
    return 0.f;
}

// ---------------------------------------------------------------------------
__global__ void prep_weights(const float* __restrict__ W1e, const float* __restrict__ b1e,
                             const float* __restrict__ W2e, const float* __restrict__ b2e,
                             const float* __restrict__ W1n, const float* __restrict__ b1n,
                             const float* __restrict__ W2n, const float* __restrict__ b2n,
                             float* __restrict__ Wf, uint4* __restrict__ fragW2,
                             uint4* __restrict__ frag1, uint4* __restrict__ frag2,
                             uint4* __restrict__ fragE, uint4* __restrict__ fragN) {
    int t = blockIdx.x * blockDim.x + threadIdx.x;
    int T = gridDim.x * blockDim.x;
    for (int idx = t; idx < 32; idx += T)   Wf[OFF_B1E + idx] = b1e[idx];
    for (int idx = t; idx < 64; idx += T)   Wf[OFF_B2E + idx] = b2e[idx] * TANH_SCALE;
    for (int idx = t; idx < 64; idx += T)   Wf[OFF_B2N + idx] = b2n[idx];
    for (int idx = t; idx < 32; idx += T)   Wf[OFF_B1N + idx] = b1n[idx];
    for (int idx = t; idx < 32; idx += T) {
        Wf[OFF_W1POS + 2 * idx + 0] = W1e[2 * 32 + idx];
        Wf[OFF_W1POS + 2 * idx + 1] = W1e[3 * 32 + idx];
    }
    // MFMA B-fragments for W2e (bf16, pre-scaled), 4 N-tiles x 64 lanes x 16B
    for (int idx = t; idx < 256; idx += T) {
        int tt = idx >> 6, l = idx & 63;
        int colv = l & 15, quadv = l >> 4;
        uint4 v;
        unsigned pk[4];
#pragma unroll
        for (int pr = 0; pr < 4; pr++) {
            int j0 = quadv * 8 + 2 * pr;
            float f0 = W2e[j0 * 64 + 16 * tt + colv] * TANH_SCALE;
            float f1 = W2e[(j0 + 1) * 64 + 16 * tt + colv] * TANH_SCALE;
            pk[pr] = f2bf_pair(f0, f1);
        }
        v.x = pk[0]; v.y = pk[1]; v.z = pk[2]; v.w = pk[3];
        fragW2[tt * 64 + l] = v;
    }
    // node layer-1 B-frags (sumh part): B[i][j] = W1n[(66+i)*32+j], hi/lo
    for (int idx = t; idx < 512; idx += T) {
        int l = idx & 63, rest = idx >> 6;
        int hl = rest & 1, tt = (rest >> 1) & 1, kc = rest >> 2;
        int colv = l & 15, quadv = l >> 4;
        unsigned pk[4];
#pragma unroll
        for (int pr = 0; pr < 4; pr++) {
            int i0 = kc * 32 + quadv * 8 + 2 * pr;
            float f0 = W1n[(66 + i0) * 32 + tt * 16 + colv];
            float f1 = W1n[(66 + i0 + 1) * 32 + tt * 16 + colv];
            if (hl) { f0 -= bf_round(f0); f1 -= bf_round(f1); }
            pk[pr] = f2bf_pair(f0, f1);
        }
        uint4 v; v.x = pk[0]; v.y = pk[1]; v.z = pk[2]; v.w = pk[3];
        frag1[idx] = v;
    }
    // node layer-2 B-frags: B[j][k] = W2n[j*64+k]*TANH_SCALE, hi/lo
    for (int idx = t; idx < 512; idx += T) {
        int l = idx & 63, rest = idx >> 6;
        int hl = rest & 1, tt = rest >> 1;
        int colv = l & 15, quadv = l >> 4;
        unsigned pk[4];
#pragma unroll
        for (int pr = 0; pr < 4; pr++) {
            int j0 = quadv * 8 + 2 * pr;
            float f0 = W2n[j0 * 64 + tt * 16 + colv] * TANH_SCALE;
            float f1 = W2n[(j0 + 1) * 64 + tt * 16 + colv] * TANH_SCALE;
            if (hl) { f0 -= bf_round(f0); f1 -= bf_round(f1); }
            pk[pr] = f2bf_pair(f0, f1);
        }
        uint4 v; v.x = pk[0]; v.y = pk[1]; v.z = pk[2]; v.w = pk[3];
        frag2[idx] = v;
    }
    // phase1 precompute B-frags over X96: fragE / fragN, [kc(3)][tt(2)][hl(2)][64]
    for (int idx = t; idx < 768; idx += T) {
        int l = idx & 63, rest = idx >> 6;
        int hl = rest & 1, tt = (rest >> 1) & 1, kc = rest >> 2;
        int colv = l & 15, quadv = l >> 4;
        int j = tt * 16 + colv;
        unsigned pkE[4], pkN[4];
#pragma unroll
        for (int pr = 0; pr < 4; pr++) {
            int i0 = kc * 32 + quadv * 8 + 2 * pr;
            float e0 = w1e_x96(W1e, i0, j), e1 = w1e_x96(W1e, i0 + 1, j);
            float n0 = w1n_x96(W1n, i0, j), n1 = w1n_x96(W1n, i0 + 1, j);
            if (hl) {
                e0 -= bf_round(e0); e1 -= bf_round(e1);
                n0 -= bf_round(n0); n1 -= bf_round(n1);
            }
            pkE[pr] = f2bf_pair(e0, e1);
            pkN[pr] = f2bf_pair(n0, n1);
        }
        uint4 ve; ve.x = pkE[0]; ve.y = pkE[1]; ve.z = pkE[2]; ve.w = pkE[3];
        uint4 vn; vn.x = pkN[0]; vn.y = pkN[1]; vn.z = pkN[2]; vn.w = pkN[3];
        fragE[idx] = ve;
        fragN[idx] = vn;
    }
}

// ---------------------------------------------------------------------------
// k_preSort: blocks [0,NSORT) = block-local counting sort (512t, no global
// atomics); blocks [NSORT, ...) = MFMA per-node precompute, 8 groups of 16
// nodes per block (wave-private LDS tiles, no barrier). LDS = 36KB union.
// ---------------------------------------------------------------------------
__global__ __launch_bounds__(512) void k_preSort(
    const float* __restrict__ hbuf, const float* __restrict__ ubuf,
    const float* __restrict__ posbuf, const float* __restrict__ Wf,
    const uint4* __restrict__ fragE, const uint4* __restrict__ fragN,
    uint4* __restrict__ Abf, float* __restrict__ A2,
    const int* __restrict__ src, const int* __restrict__ dst,
    unsigned* __restrict__ blockbuf, unsigned* __restrict__ packoff,
    int E, int N, int NSORT) {
    __shared__ __align__(16) char smem[36864];
    int tid = threadIdx.x;

    if ((int)blockIdx.x < NSORT) {
        // ---- sort path ----
        int* cnt = (int*)smem;
        int* scn = cnt + 512;
        int* exc = scn + 512;
        int* cur = exc + 512;
        unsigned* sorted = (unsigned*)(cur + 512);   // 4096 u32 = 16KB
        int k = blockIdx.x;
        int e0 = k * EPB;
        cnt[tid] = 0; cur[tid] = 0;
        __syncthreads();
        int bs[8]; unsigned pv[8];
#pragma unroll
        for (int j = 0; j < 8; j++) {
            int e = e0 + j * 512 + tid;
            if (e < E) {
                int d = dst[e];
                bs[j] = d >> BUCK_SHIFT;
                pv[j] = (unsigned)src[e] | ((unsigned)(d & 255) << 20);
                atomicAdd(&cnt[bs[j]], 1);
            } else bs[j] = -1;
        }
        __syncthreads();
        scn[tid] = cnt[tid];
        __syncthreads();
        for (int st = 1; st < 512; st <<= 1) {
            int add = (tid >= st) ? scn[tid - st] : 0;
            __syncthreads();
            scn[tid] += add;
            __syncthreads();
        }
        int ex = scn[tid] - cnt[tid];
        exc[tid] = ex;
        packoff[(size_t)tid * 512 + k] = ((unsigned)ex << 13) | (unsigned)cnt[tid];
        __syncthreads();
        int tot = scn[511];
#pragma unroll
        for (int j = 0; j < 8; j++) {
            if (bs[j] >= 0) {
                int slot = exc[bs[j]] + atomicAdd(&cur[bs[j]], 1);
                sorted[slot] = pv[j];
            }
        }
        __syncthreads();
#pragma unroll
        for (int j = 0; j < 8; j++) {
            int i = j * 512 + tid;
            if (i < tot) blockbuf[(size_t)k * EPB + i] = sorted[i];
        }
        return;
    }

    // ---- pre path: 8 groups of 16 nodes per block ----
    float* tiles = (float*)smem;                     // 8 waves x 1152 floats
    int wv = tid >> 6, lane = tid & 63;
    int col = lane & 15, quad = lane >> 4;
    int g = ((int)blockIdx.x - NSORT) * 8 + wv;
    int ngroups = (N + 15) >> 4;
    if (g >= ngroups) return;
    int nbase = g * 16;
    int nA = nbase + col; nA = (nA < N) ? nA : (N - 1);

    bf16x8 xh[3], xl[3];
    {
        const float* hrow = hbuf + (size_t)nA * 64 + quad * 8;
        float4 f0 = *(const float4*)(hrow);
        float4 f1 = *(const float4*)(hrow + 4);
        xh[0] = pack8(f0.x, f0.y, f0.z, f0.w, f1.x, f1.y, f1.z, f1.w);
        xl[0] = pack8(f0.x - bf_round(f0.x), f0.y - bf_round(f0.y),
                      f0.z - bf_round(f0.z), f0.w - bf_round(f0.w),
                      f1.x - bf_round(f1.x), f1.y - bf_round(f1.y),
                      f1.z - bf_round(f1.z), f1.w - bf_round(f1.w));
        float4 g0 = *(const float4*)(hrow + 32);
        float4 g1 = *(const float4*)(hrow + 36);
        xh[1] = pack8(g0.x, g0.y, g0.z, g0.w, g1.x, g1.y, g1.z, g1.w);
        xl[1] = pack8(g0.x - bf_round(g0.x), g0.y - bf_round(g0.y),
                      g0.z - bf_round(g0.z), g0.w - bf_round(g0.w),
                      g1.x - bf_round(g1.x), g1.y - bf_round(g1.y),
                      g1.z - bf_round(g1.z), g1.w - bf_round(g1.w));
    }
    {
        float xv[8];
#pragma unroll
        for (int i = 0; i < 8; i++) xv[i] = 0.f;
        if (quad == 0) {
            float2 pp = ((const float2*)posbuf)[nA];
            float4 uu = ((const float4*)ubuf)[(size_t)nA * 2];
            xv[0] = pp.x; xv[1] = pp.y;
            xv[4] = uu.x; xv[5] = uu.y; xv[6] = uu.z; xv[7] = uu.w;
        } else if (quad == 1) {
            float4 ub = ((const float4*)ubuf)[(size_t)nA * 2 + 1];
            xv[0] = ub.x; xv[1] = ub.y; xv[2] = ub.z; xv[3] = ub.w;
        }
        xh[2] = pack8(xv[0], xv[1], xv[2], xv[3], xv[4], xv[5], xv[6], xv[7]);
        xl[2] = pack8(xv[0] - bf_round(xv[0]), xv[1] - bf_round(xv[1]),
                      xv[2] - bf_round(xv[2]), xv[3] - bf_round(xv[3]),
                      xv[4] - bf_round(xv[4]), xv[5] - bf_round(xv[5]),
                      xv[6] - bf_round(xv[6]), xv[7] - bf_round(xv[7]));
    }

    f32x4 accE[2], accN[2];
#pragma unroll
    for (int t = 0; t < 2; t++) {
        float be = Wf[OFF_B1E + t * 16 + col];
        float bn = Wf[OFF_B1N + t * 16 + col];
        f32x4 e = {be, be, be, be}; accE[t] = e;
        f32x4 n = {bn, bn, bn, bn}; accN[t] = n;
    }
#pragma unroll
    for (int kc = 0; kc < 3; kc++) {
#pragma unroll
        for (int t = 0; t < 2; t++) {
            union { uint4 u; bf16x8 b; } bh, bl;
            int fi = ((kc * 2 + t) * 2) * 64 + lane;
            bh.u = fragE[fi]; bl.u = fragE[fi + 64];
            accE[t] = __builtin_amdgcn_mfma_f32_16x16x32_bf16(xh[kc], bh.b, accE[t], 0, 0, 0);
            accE[t] = __builtin_amdgcn_mfma_f32_16x16x32_bf16(xh[kc], bl.b, accE[t], 0, 0, 0);
            accE[t] = __builtin_amdgcn_mfma_f32_16x16x32_bf16(xl[kc], bh.b, accE[t], 0, 0, 0);
            bh.u = fragN[fi]; bl.u = fragN[fi + 64];
            accN[t] = __builtin_amdgcn_mfma_f32_16x16x32_bf16(xh[kc], bh.b, accN[t], 0, 0, 0);
            accN[t] = __builtin_amdgcn_mfma_f32_16x16x32_bf16(xh[kc], bl.b, accN[t], 0, 0, 0);
            accN[t] = __builtin_amdgcn_mfma_f32_16x16x32_bf16(xl[kc], bh.b, accN[t], 0, 0, 0);
        }
    }

    // wave-private tiles: write then read within the same wave (no barrier)
    float* twE = tiles + wv * 1152;
    float* twN = twE + 576;
#pragma unroll
    for (int t = 0; t < 2; t++) {
#pragma unroll
        for (int r = 0; r < 4; r++) {
            twE[(quad * 4 + r) * 36 + t * 16 + col] = accE[t][r];
            twN[(quad * 4 + r) * 36 + t * 16 + col] = accN[t][r];
        }
    }
    {
        int node = lane >> 2, q = lane & 3;
        const float* tr = twE + node * 36 + q * 8;
        uint4 v;
        v.x = f2bf_pair(tr[0], tr[1]); v.y = f2bf_pair(tr[2], tr[3]);
        v.z = f2bf_pair(tr[4], tr[5]); v.w = f2bf_pair(tr[6], tr[7]);
        if (nbase + node < N) Abf[(size_t)(nbase + node) * 4 + q] = v;
    }
#pragma unroll
    for (int it = 0; it < 2; it++) {
        int fi = lane + it * 64;
        int node = fi >> 3, c = fi & 7;
        float4 fv = *(const float4*)(twN + node * 36 + c * 4);
        if (nbase + node < N)
            ((float4*)(A2 + (size_t)(nbase + node) * 32))[c] = fv;
    }
}

// ---------------------------------------------------------------------------
// k_bucketB2: per bucket, scan run lengths over sort-blocks, gather runs
// into LDS (scattered reads), deg/scan -> seg, cursor-scatter ssrc into
// the bucket's private C-region.
// ---------------------------------------------------------------------------
extern __shared__ unsigned gath[];
__global__ __launch_bounds__(512) void k_bucketB2(
    const unsigned* __restrict__ blockbuf, const unsigned* __restrict__ packoff,
    int2* __restrict__ seg, int* __restrict__ ssrc, int N, int C, int nsort) {
    __shared__ int runc[512];
    __shared__ int deg[256], scn[256], exc[256], cur[256];
    int b = blockIdx.x, tid = threadIdx.x;
    unsigned po = packoff[(size_t)b * 512 + tid];
    int rcnt = (tid < nsort) ? (int)(po & 0x1FFFu) : 0;
    int rexc = (int)(po >> 13);
    runc[tid] = rcnt;
    __syncthreads();
    for (int st = 1; st < 512; st <<= 1) {
        int add = (tid >= st) ? runc[tid - st] : 0;
        __syncthreads();
        runc[tid] += add;
        __syncthreads();
    }
    int my0 = runc[tid] - rcnt;
    int cntb = runc[511];
    cntb = (cntb < C) ? cntb : C;
    if (tid < nsort && rcnt > 0) {
        const unsigned* rb = blockbuf + (size_t)tid * EPB + rexc;
        for (int i = 0; i < rcnt; i++) {
            int o = my0 + i;
            if (o < C) gath[o] = rb[i];
        }
    }
    if (tid < 256) { deg[tid] = 0; cur[tid] = 0; }
    __syncthreads();
    for (int i = tid; i < cntb; i += 512)
        atomicAdd(&deg[gath[i] >> 20], 1);
    __syncthreads();
    if (tid < 256) scn[tid] = deg[tid];
    __syncthreads();
    for (int st = 1; st < 256; st <<= 1) {
        int add = (tid < 256 && tid >= st) ? scn[tid - st] : 0;
        __syncthreads();
        if (tid < 256) scn[tid] += add;
        __syncthreads();
    }
    if (tid < 256) {
        int ex2 = scn[tid] - deg[tid];
        exc[tid] = ex2;
        int n = (b << BUCK_SHIFT) + tid;
        if (n < N) {
            int lo = b * C + ex2;
            seg[n] = make_int2(lo, lo + deg[tid]);
        }
    }
    __syncthreads();
    size_t basep = (size_t)b * C;
    for (int i = tid; i < cntb; i += 512) {
        unsigned p = gath[i];
        int l = (int)(p >> 20);
        int slot = exc[l] + atomicAdd(&cur[l], 1);
        ssrc[basep + slot] = (int)(p & 0xFFFFFu);
    }
}

// ---------------------------------------------------------------------------
// Fused edge-MLP + gather (R11/R2 structure, verified 69.2us) with the
// unpack/+padd/lrelu chain in packed f32 pairs (v_pk_*).
// ---------------------------------------------------------------------------
__global__ __launch_bounds__(256) void fused_edge_gather(
    const int2* __restrict__ seg, const int* __restrict__ ssrc,
    const uint4* __restrict__ Abf, const float* __restrict__ posbuf,
    const float* __restrict__ Wf, const uint4* __restrict__ fragW2,
    float* __restrict__ sumh, int N, int npw) {
    int wid = blockIdx.x * 4 + (threadIdx.x >> 6);
    int lane = threadIdx.x & 63;
    int col = lane & 15, quad = lane >> 4;

    union { uint4 u; bf16x8 v; } cvt;
    bf16x8 bfr[4];
#pragma unroll
    for (int t = 0; t < 4; t++) {
        cvt.u = fragW2[t * 64 + lane];
        bfr[t] = cvt.v;
    }
    float c0[4];
#pragma unroll
    for (int t = 0; t < 4; t++) c0[t] = Wf[OFF_B2E + 16 * t + col];
    f32x2 wx2[4], wy2[4];
#pragma unroll
    for (int p = 0; p < 4; p++) {
        float2 wa = ((const float2*)(Wf + OFF_W1POS))[quad * 8 + 2 * p];
        float2 wb = ((const float2*)(Wf + OFF_W1POS))[quad * 8 + 2 * p + 1];
        wx2[p].x = wa.x; wx2[p].y = wb.x;
        wy2[p].x = wa.y; wy2[p].y = wb.y;
    }

    int n0 = wid * npw;
    int n1 = n0 + npw; n1 = (n1 < N) ? n1 : N;
#pragma unroll 1
    for (int n = n0; n < n1; n++) {
        int2 sg = seg[n];
        int lo = sg.x, hi = sg.y, deg = hi - lo;
        float2 pd = ((const float2*)posbuf)[n];
        f32x2 padd2[4];
#pragma unroll
        for (int p = 0; p < 4; p++)
            padd2[p] = pd.x * wx2[p] + pd.y * wy2[p];

        float s0[4] = {0.f, 0.f, 0.f, 0.f};
        if (deg > 0) {
            int te = lo + col;
            te = (te < hi) ? te : (hi - 1);
            uint4 ar = Abf[(size_t)ssrc[te] * 4 + quad];
            int nfull = deg & ~15;
#pragma unroll 1
            for (int b = 0; b < nfull; b += 16) {
                // prefetch next batch (clamped; harmless re-read at the end)
                int teN = lo + b + 16 + col;
                teN = (teN < hi) ? teN : (hi - 1);
                uint4 arN = Abf[(size_t)ssrc[teN] * 4 + quad];

                bf16x8 af;
                {
                    f32x2 v01 = unpk2(ar.x) + padd2[0];
                    f32x2 v23 = unpk2(ar.y) + padd2[1];
                    f32x2 v45 = unpk2(ar.z) + padd2[2];
                    f32x2 v67 = unpk2(ar.w) + padd2[3];
                    v01 = __builtin_elementwise_max(v01, v01 * LRELU_SLOPE);
                    v23 = __builtin_elementwise_max(v23, v23 * LRELU_SLOPE);
                    v45 = __builtin_elementwise_max(v45, v45 * LRELU_SLOPE);
                    v67 = __builtin_elementwise_max(v67, v67 * LRELU_SLOPE);
                    af[0] = (__bf16)v01.x; af[1] = (__bf16)v01.y;
                    af[2] = (__bf16)v23.x; af[3] = (__bf16)v23.y;
                    af[4] = (__bf16)v45.x; af[5] = (__bf16)v45.y;
                    af[6] = (__bf16)v67.x; af[7] = (__bf16)v67.y;
                }
#pragma unroll
                for (int t = 0; t < 4; t++) {
                    f32x4 acc = {c0[t], c0[t], c0[t], c0[t]};
                    acc = __builtin_amdgcn_mfma_f32_16x16x32_bf16(af, bfr[t], acc, 0, 0, 0);
                    float u0 = __builtin_amdgcn_exp2f(acc[0]);
                    float u1 = __builtin_amdgcn_exp2f(acc[1]);
                    float u2 = __builtin_amdgcn_exp2f(acc[2]);
                    float u3 = __builtin_amdgcn_exp2f(acc[3]);
                    float q01 = u0 + u1, q23 = u2 + u3;
                    float d01 = fmaf(u0, u1, q01) + 1.f;
                    float d23 = fmaf(u2, u3, q23) + 1.f;
                    s0[t] = fmaf(q01 + 2.f, __builtin_amdgcn_rcpf(d01), s0[t]);
                    s0[t] = fmaf(q23 + 2.f, __builtin_amdgcn_rcpf(d23), s0[t]);
                }
                ar = arN;
            }
            int tail = deg - nfull;
            if (tail) {
                bf16x8 af;
                {
                    f32x2 v01 = unpk2(ar.x) + padd2[0];
                    f32x2 v23 = unpk2(ar.y) + padd2[1];
                    f32x2 v45 = unpk2(ar.z) + padd2[2];
                    f32x2 v67 = unpk2(ar.w) + padd2[3];
                    v01 = __builtin_elementwise_max(v01, v01 * LRELU_SLOPE);
                    v23 = __builtin_elementwise_max(v23, v23 * LRELU_SLOPE);
                    v45 = __builtin_elementwise_max(v45, v45 * LRELU_SLOPE);
                    v67 = __builtin_elementwise_max(v67, v67 * LRELU_SLOPE);
                    af[0] = (__bf16)v01.x; af[1] = (__bf16)v01.y;
                    af[2] = (__bf16)v23.x; af[3] = (__bf16)v23.y;
                    af[4] = (__bf16)v45.x; af[5] = (__bf16)v45.y;
                    af[6] = (__bf16)v67.x; af[7] = (__bf16)v67.y;
                }
                int rowb = quad * 4;
#pragma unroll
                for (int t = 0; t < 4; t++) {
                    f32x4 acc = {c0[t], c0[t], c0[t], c0[t]};
                    acc = __builtin_amdgcn_mfma_f32_16x16x32_bf16(af, bfr[t], acc, 0, 0, 0);
                    // invalid rows: u = 1e30 -> pair algebra makes the
                    // contribution ~2^-60 (drops out); double-invalid ~0.
                    float u0 = (rowb + 0 < tail) ? __builtin_amdgcn_exp2f(acc[0]) : 1e30f;
                    float u1 = (rowb + 1 < tail) ? __builtin_amdgcn_exp2f(acc[1]) : 1e30f;
                    float u2 = (rowb + 2 < tail) ? __builtin_amdgcn_exp2f(acc[2]) : 1e30f;
                    float u3 = (rowb + 3 < tail) ? __builtin_amdgcn_exp2f(acc[3]) : 1e30f;
                    float q01 = u0 + u1, q23 = u2 + u3;
                    float d01 = fmaf(u0, u1, q01) + 1.f;
                    float d23 = fmaf(u2, u3, q23) + 1.f;
                    s0[t] = fmaf(q01 + 2.f, __builtin_amdgcn_rcpf(d01), s0[t]);
                    s0[t] = fmaf(q23 + 2.f, __builtin_amdgcn_rcpf(d23), s0[t]);
                }
            }
        }
#pragma unroll
        for (int t = 0; t < 4; t++) {
            s0[t] += __shfl_xor(s0[t], 16);
            s0[t] += __shfl_xor(s0[t], 32);
        }
        if (lane < 16) {
            float* sr = sumh + (size_t)n * 64;
            float fd = (float)deg;
#pragma unroll
            for (int t = 0; t < 4; t++) sr[16 * t + lane] = fmaf(-2.f, s0[t], fd);
        }
    }
}

// ---------------------------------------------------------------------------
// Node MLP via MFMA: 16 nodes per wave (verified R19, ~19us).
// ---------------------------------------------------------------------------
__global__ __launch_bounds__(256) void k_node4(
    const float* __restrict__ A2, const float* __restrict__ sumh,
    const float* __restrict__ Wf, const uint4* __restrict__ frag1,
    const uint4* __restrict__ frag2, float* __restrict__ out,
    int N, int ngroups) {
    __shared__ float ylds[4 * 16 * 36];   // per-wave [16 nodes][32 y + pad4]
    int wv = threadIdx.x >> 6, lane = threadIdx.x & 63;
    int col = lane & 15, quad = lane >> 4;
    int g = blockIdx.x * 4 + wv;
    bool live = (g < ngroups);
    int gc = live ? g : (ngroups - 1);
    int nbase = gc * 16;

    int nA = nbase + col; nA = (nA < N) ? nA : (N - 1);
    const float* srow = sumh + (size_t)nA * 64 + quad * 8;
    bf16x8 sh[2], sl[2];
#pragma unroll
    for (int kc = 0; kc < 2; kc++) {
        float4 f0 = *(const float4*)(srow + kc * 32);
        float4 f1 = *(const float4*)(srow + kc * 32 + 4);
        sh[kc] = pack8(f0.x, f0.y, f0.z, f0.w, f1.x, f1.y, f1.z, f1.w);
        sl[kc] = pack8(f0.x - bf_round(f0.x), f0.y - bf_round(f0.y),
                       f0.z - bf_round(f0.z), f0.w - bf_round(f0.w),
                       f1.x - bf_round(f1.x), f1.y - bf_round(f1.y),
                       f1.z - bf_round(f1.z), f1.w - bf_round(f1.w));
    }

    f32x4 acc1[2];
#pragma unroll
    for (int t = 0; t < 2; t++) { f32x4 z = {0.f, 0.f, 0.f, 0.f}; acc1[t] = z; }
#pragma unroll
    for (int kc = 0; kc < 2; kc++) {
#pragma unroll
        for (int t = 0; t < 2; t++) {
            union { uint4 u; bf16x8 b; } bh, bl;
            bh.u = frag1[((kc * 2 + t) * 2 + 0) * 64 + lane];
            bl.u = frag1[((kc * 2 + t) * 2 + 1) * 64 + lane];
            acc1[t] = __builtin_amdgcn_mfma_f32_16x16x32_bf16(sh[kc], bh.b, acc1[t], 0, 0, 0);
            acc1[t] = __builtin_amdgcn_mfma_f32_16x16x32_bf16(sh[kc], bl.b, acc1[t], 0, 0, 0);
            acc1[t] = __builtin_amdgcn_mfma_f32_16x16x32_bf16(sl[kc], bh.b, acc1[t], 0, 0, 0);
        }
    }

    float* yw = ylds + wv * 576;
#pragma unroll
    for (int t = 0; t < 2; t++) {
#pragma unroll
        for (int r = 0; r < 4; r++) {
            int ndr = quad * 4 + r;
            int nd = nbase + ndr; nd = (nd < N) ? nd : (N - 1);
            float yv = acc1[t][r] + A2[(size_t)nd * 32 + t * 16 + col];
            yv = fmaxf(yv, LRELU_SLOPE * yv);
            yw[ndr * 36 + t * 16 + col] = yv;
        }
    }
    __syncthreads();

    const float* yr = ylds + wv * 576 + col * 36 + quad * 8;
    float4 y0 = *(const float4*)(yr);
    float4 y1 = *(const float4*)(yr + 4);
    bf16x8 yh = pack8(y0.x, y0.y, y0.z, y0.w, y1.x, y1.y, y1.z, y1.w);
    bf16x8 yl = pack8(y0.x - bf_round(y0.x), y0.y - bf_round(y0.y),
                      y0.z - bf_round(y0.z), y0.w - bf_round(y0.w),
                      y1.x - bf_round(y1.x), y1.y - bf_round(y1.y),
                      y1.z - bf_round(y1.z), y1.w - bf_round(y1.w));

    f32x4 acc2[4];
#pragma unroll
    for (int t = 0; t < 4; t++) {
        float b = Wf[OFF_B2N + t * 16 + col] * TANH_SCALE;
        f32x4 z = {b, b, b, b}; acc2[t] = z;
    }
#pragma unroll
    for (int t = 0; t < 4; t++) {
        union { uint4 u; bf16x8 b; } bh, bl;
        bh.u = frag2[(t * 2 + 0) * 64 + lane];
        bl.u = frag2[(t * 2 + 1) * 64 + lane];
        acc2[t] = __builtin_amdgcn_mfma_f32_16x16x32_bf16(yh, bh.b, acc2[t], 0, 0, 0);
        acc2[t] = __builtin_amdgcn_mfma_f32_16x16x32_bf16(yh, bl.b, acc2[t], 0, 0, 0);
        acc2[t] = __builtin_amdgcn_mfma_f32_16x16x32_bf16(yl, bh.b, acc2[t], 0, 0, 0);
    }
    if (live) {
#pragma unroll
        for (int t = 0; t < 4; t++) {
#pragma unroll
            for (int r = 0; r < 4; r++) {
                int nd = nbase + quad * 4 + r;
                if (nd < N) {
                    float e = __builtin_amdgcn_exp2f(acc2[t][r]);
                    out[(size_t)nd * 64 + t * 16 + col] =
                        1.f - 2.f * __builtin_amdgcn_rcpf(e + 1.f);
                }
            }
        }
    }
}

// ---------------------------------------------------------------------------
extern "C" void kernel_launch(void* const* d_in, const int* in_sizes, int n_in,
                              void* d_out, int out_size, void* d_ws, size_t ws_size,
                              hipStream_t stream) {
    const float* hbuf   = (const float*)d_in[0];
    const float* ubuf   = (const float*)d_in[1];
    const float* posbuf = (const float*)d_in[2];
    const int* src = (const int*)d_in[3];
    const int* dst = (const int*)d_in[4];

    int N = in_sizes[0] / 64;
    int E = in_sizes[3];
    int NBUCK = (N + 255) >> BUCK_SHIFT;                 // 256-node buckets
    int C = ((2 * ((E + NBUCK - 1) / NBUCK)) + 255) & ~255;  // bucket capacity
    int NSORT = (E + EPB - 1) / EPB;                     // sort blocks (<=512)

    char* p = (char*)d_ws;
    auto alloc = [&](size_t bytes) {
        char* r = p;
        p += (bytes + 255) & ~(size_t)255;
        return r;
    };
    float*    Wf       = (float*)alloc(W_TOTAL * 4);
    uint4*    fragW2   = (uint4*)alloc(4 * 64 * 16);
    uint4*    frag1    = (uint4*)alloc(512 * 16);
    uint4*    frag2    = (uint4*)alloc(512 * 16);
    uint4*    fragE    = (uint4*)alloc(768 * 16);
    uint4*    fragN    = (uint4*)alloc(768 * 16);
    uint4*    Abf      = (uint4*)alloc((size_t)N * 64);  // bf16 A rows, 64B
    float*    A2       = (float*)alloc((size_t)N * 32 * 4);
    float*    sumh     = (float*)alloc((size_t)N * 64 * 4);
    int2*     seg      = (int2*)alloc((size_t)N * 8);
    unsigned* blockbuf = (unsigned*)alloc((size_t)NSORT * EPB * 4);
    unsigned* packoff  = (unsigned*)alloc((size_t)512 * 512 * 4);
    int*      ssrc     = (int*)alloc((size_t)NBUCK * C * 4);

    prep_weights<<<32, 256, 0, stream>>>(
        (const float*)d_in[5], (const float*)d_in[6],
        (const float*)d_in[7], (const float*)d_in[8],
        (const float*)d_in[9], (const float*)d_in[10],
        (const float*)d_in[11], (const float*)d_in[12], Wf, fragW2,
        frag1, frag2, fragE, fragN);

    int ngroups = (N + 15) / 16;
    int nblkPre = (ngroups + 7) / 8;
    k_preSort<<<NSORT + nblkPre, 512, 0, stream>>>(
        hbuf, ubuf, posbuf, Wf, fragE, fragN, Abf, A2,
        src, dst, blockbuf, packoff, E, N, NSORT);

    k_bucketB2<<<NBUCK, 512, (size_t)C * 4, stream>>>(
        blockbuf, packoff, seg, ssrc, N, C, NSORT);

    const int FBLK = 2048;                    // 8192 waves = full machine
    int npw = (N + FBLK * 4 - 1) / (FBLK * 4);
    fused_edge_gather<<<FBLK, 256, 0, stream>>>(
        seg, ssrc, Abf, posbuf, Wf, fragW2, sumh, N, npw);

    k_node4<<<(ngroups + 3) / 4, 256, 0, stream>>>(
        A2, sumh, Wf, frag1, frag2, (float*)d_out, N, ngroups);
}